// Round 19
// baseline (1466.996 us; speedup 1.0000x reference)
//
#include <hip/hip_runtime.h>

// ObjectMsgEncoder on MI355X. f32 I/O, bf16 MFMA internally (f32 accumulate).
// R18 -> R19: exp-once epilogue in k_mega. VALU audit: the epilogue's ~56
// serial __expf/thread (lseB scan + output loop) + 5-op swizzle per scalar LDS
// access dominate VALUBusy 38%. Now S5 writes BOTH v=resa (Yb) and E=exp(v)
// (Xa, dead after the Wesa GEMM; one extra barrier). Column pass sums E
// (no exp/log) -> hrSB = 0.5/sumE; gaussian stores G=exp(gscore), hrSG=0.5/sumG;
// output loop: a = E*hrSB + G*hrSG, s += a*v -- zero transcendentals.
// Attention still normalizes exactly (same rounded E in num and denom).
// Everything else byte-identical to R18 (best: 1464 us).

typedef __attribute__((ext_vector_type(8))) short short8;
typedef __attribute__((ext_vector_type(4))) float f32x4;

__device__ __forceinline__ float b2f(unsigned short u){
  union { unsigned int i; float f; } v; v.i = ((unsigned int)u) << 16; return v.f;
}
__device__ __forceinline__ unsigned short f2b(float f){
  union { float f; unsigned int i; } v; v.f = f;
  return (unsigned short)((v.i + 0x8000u) >> 16);   // round-half-up, 2 ops
}
__device__ __forceinline__ float sigm(float x){ return 1.f/(1.f+__expf(-x)); }
__device__ __forceinline__ float tanh_f(float x){ float e = __expf(2.f*x); return 1.f - 2.f/(e+1.f); }
// LDS swizzle: 8-element (16B) chunks, phys chunk = (c&24) | ((c^row)&7).
__device__ __forceinline__ int xsw(int row, int n){
  int c = n >> 3;
  int pc = (c & 24) | ((c ^ row) & 7);
  return row*256 + pc*8 + (n & 7);
}
__device__ __forceinline__ int xchunk(int row, int c){
  return row*256 + ((c & 24) | ((c ^ row) & 7))*8;
}

#define MFMA16(a,b,c) __builtin_amdgcn_mfma_f32_16x16x32_bf16((a),(b),(c),0,0,0)

// ---------------- K0: one-shot repack of all 7 weight blocks + wmean ----------------
__global__ __launch_bounds__(256) void k_repack7(const float* __restrict__ Wih,
                                                 const float* __restrict__ Whh,
                                                 const float* __restrict__ Wgr,
                                                 const float* __restrict__ Wbc,
                                                 const float* __restrict__ Wesa,
                                                 const float* __restrict__ Wmu,
                                                 unsigned short* __restrict__ wcv,
                                                 float* __restrict__ wmean){
  int i = blockIdx.x*256 + threadIdx.x;
  if (i >= 851968){                      // tail block: wmean
    int o = i - 851968;
    if (o < 256) wmean[o] = (Wmu[o] + Wmu[256+o] + Wmu[512+o]) * (1.f/3.f);
    return;
  }
  const float* s; int segbase, N, stride, off, local;
  if      (i < 262144){ s=Wih;  segbase=0;      N=1024; stride=256; off=0;   local=i; }
  else if (i < 524288){ s=Whh;  segbase=262144; N=1024; stride=256; off=0;   local=i-262144; }
  else if (i < 589824){ s=Wgr;  segbase=524288; N=256;  stride=768; off=0;   local=i-524288; }
  else if (i < 655360){ s=Wgr;  segbase=589824; N=256;  stride=768; off=256; local=i-589824; }
  else if (i < 720896){ s=Wgr;  segbase=655360; N=256;  stride=768; off=512; local=i-655360; }
  else if (i < 786432){ s=Wbc;  segbase=720896; N=256;  stride=256; off=0;   local=i-720896; }
  else                { s=Wesa; segbase=786432; N=256;  stride=256; off=0;   local=i-786432; }
  int n = local >> 8, k = local & 255;
  wcv[segbase + (((k >> 3)*N + n) << 3) + (k & 7)] = f2b(s[n*stride + off + k]);
}

// ---------------- K1: olf0 = emb * mask (f32 -> bf16) + zero outacc ----------------
__global__ __launch_bounds__(256) void k_prep(const float* __restrict__ emb,
                                              const int* __restrict__ counts,
                                              unsigned short* __restrict__ olf,
                                              float* __restrict__ outacc){
  int bs = blockIdx.x;            // b*28+s
  int b = bs / 28; int s = bs - b*28;
  int e = threadIdx.x;
  olf[(size_t)bs*256 + e] = (s < counts[b]) ? f2b(emb[(size_t)bs*256 + e]) : (unsigned short)0;
  outacc[(size_t)bs*256 + e] = 0.f;
}

// ---------------- K2a: zx = olf_l @ Wih^T  [7168,256]@[256,1024] -> bf16 ----------------
__global__ __launch_bounds__(256) void k_xgemm(const unsigned short* __restrict__ olf,
                                               const unsigned short* __restrict__ Wih,
                                               unsigned short* __restrict__ zx){
  const int tid = threadIdx.x;
  const int wid = tid >> 6, lane = tid & 63, col = lane & 15, quad = lane >> 4;
  const int m0 = blockIdx.x*64 + wid*16;
  short8 af[8];
  #pragma unroll
  for (int kt=0; kt<8; ++kt)
    af[kt] = *(const short8*)&olf[(size_t)(m0 + col)*256 + kt*32 + quad*8];
  #pragma unroll 4
  for (int nt=0; nt<64; ++nt){
    int n = nt*16 + col;
    f32x4 acc = (f32x4){0.f,0.f,0.f,0.f};
    #pragma unroll
    for (int kt=0; kt<8; ++kt){
      short8 bf = *(const short8*)&Wih[((((kt*4 + quad) << 10) + n) << 3)];
      acc = MFMA16(af[kt], bf, acc);
    }
    #pragma unroll
    for (int r=0; r<4; ++r)
      zx[(size_t)(m0 + quad*4 + r)*1024 + n] = f2b(acc[r]);
  }
}

// ---------------- K2b: LSTM recurrence: 16 blocks x 16 scenes, 1024 thr, ping-pong h ----------------
__global__ __launch_bounds__(1024) void k_rec(const unsigned short* __restrict__ zx,
                                              const unsigned short* __restrict__ Whh,
                                              const float* __restrict__ bih,
                                              const float* __restrict__ bhh,
                                              const int* __restrict__ counts,
                                              unsigned short* __restrict__ olf_out){
  __shared__ unsigned short Ab[2][16*264];   // ping-pong h buffers
  const int tid = threadIdx.x;
  const int wv = tid >> 6, lane = tid & 63, col = lane & 15, quad = lane >> 4;
  const int sc0 = blockIdx.x * 16;
  const int u = wv*16 + col;

  float bz[4];
  #pragma unroll
  for (int g=0; g<4; ++g) bz[g] = bih[g*256+u] + bhh[g*256+u];
  int cnt4[4];
  #pragma unroll
  for (int r=0; r<4; ++r) cnt4[r] = counts[sc0 + quad*4 + r];

  float cst[4];
  #pragma unroll
  for (int r=0; r<4; ++r) cst[r] = 0.f;
  for (int i=tid; i<16*264; i+=1024) Ab[0][i] = 0;   // h0 = 0
  __syncthreads();

  for (int t=0; t<28; ++t){
    const int cur = t & 1, nxt = cur ^ 1;
    float zxv[4][4];
    #pragma unroll
    for (int g=0; g<4; ++g){
      #pragma unroll
      for (int r=0; r<4; ++r)
        zxv[g][r] = b2f(zx[((size_t)(sc0 + quad*4 + r)*28 + t)*1024 + g*256 + u]);
    }
    f32x4 acc[4];
    #pragma unroll
    for (int g=0; g<4; ++g) acc[g] = (f32x4){0.f,0.f,0.f,0.f};
    #pragma unroll
    for (int kt=0; kt<8; ++kt){
      short8 a = *(const short8*)&Ab[cur][col*264 + kt*32 + quad*8];
      #pragma unroll
      for (int g=0; g<4; ++g){
        short8 bf = *(const short8*)&Whh[((((kt*4 + quad) << 10) + g*256 + u) << 3)];
        acc[g] = MFMA16(a, bf, acc[g]);
      }
    }
    // no barrier: writes go to Ab[nxt], readers used Ab[cur]
    #pragma unroll
    for (int r=0; r<4; ++r){
      int s = quad*4 + r;
      float zi = acc[0][r] + zxv[0][r] + bz[0];
      float zf = acc[1][r] + zxv[1][r] + bz[1];
      float zg = acc[2][r] + zxv[2][r] + bz[2];
      float zo = acc[3][r] + zxv[3][r] + bz[3];
      float cc = sigm(zf)*cst[r] + sigm(zi)*tanh_f(zg);
      cst[r] = cc;
      float hh = sigm(zo)*tanh_f(cc);
      unsigned short hb = f2b(hh);
      Ab[nxt][s*264 + u] = hb;                              // raw h feeds recurrence
      olf_out[((size_t)(sc0+s)*28 + t)*256 + u] = (t < cnt4[r]) ? hb : (unsigned short)0;
    }
    __syncthreads();   // Ab[nxt] complete before step t+1 reads it
  }
}

// ---------------- K3: A-terms, [21504,256]@[256,512] -> bf16 ----------------
__global__ __launch_bounds__(256) void k_aterm(const unsigned short* __restrict__ olf,
                                               const unsigned short* __restrict__ Wgri,
                                               const unsigned short* __restrict__ Wgrj,
                                               unsigned short* __restrict__ Aout){
  const int tid = threadIdx.x;
  const int wid = tid >> 6, lane = tid & 63, col = lane & 15, quad = lane >> 4;
  const int m0 = blockIdx.x*64 + wid*16;
  short8 af[8];
  #pragma unroll
  for (int kt=0; kt<8; ++kt)
    af[kt] = *(const short8*)&olf[(size_t)(m0 + col)*256 + kt*32 + quad*8];
  #pragma unroll 4
  for (int nt=0; nt<32; ++nt){
    const unsigned short* wb = (nt < 16) ? Wgri : Wgrj;
    int nn = (nt & 15)*16 + col;           // 0..255 within the submatrix
    f32x4 acc = (f32x4){0.f,0.f,0.f,0.f};
    #pragma unroll
    for (int kt=0; kt<8; ++kt){
      short8 bf = *(const short8*)&wb[((((kt*4 + quad) << 8) + nn) << 3)];
      acc = MFMA16(af[kt], bf, acc);
    }
    #pragma unroll
    for (int r=0; r<4; ++r)
      Aout[(size_t)(m0 + quad*4 + r)*512 + nt*16 + col] = f2b(acc[r]);
  }
}

// ---------------- K4: fused per-(scene, j-pair), ping-pong LDS ----------------
// 3584 blocks x 512 thr (8 waves). Row p = i*2 + jc (i<28, jc<2) -> 56 rows
// padded to 64. Wave wv owns cols wv*32..+31 for all 64 rows. Xa/Yb 2x32KB.
// Weights fragment-major, N=256.
#define GEMM_TILE64(SRC, WPTR)                                                      \
  {                                                                                 \
    _Pragma("unroll")                                                               \
    for (int rf=0; rf<4; ++rf){ Ya[rf][0]=(f32x4){0.f,0.f,0.f,0.f};                 \
                                Ya[rf][1]=(f32x4){0.f,0.f,0.f,0.f}; }               \
    _Pragma("unroll 1")                                                             \
    for (int kc=0; kc<4; ++kc){                                                     \
      short8 av[2][4], bv[2][2];                                                    \
      _Pragma("unroll")                                                             \
      for (int u=0; u<2; ++u){                                                      \
        int kt = kc*2 + u; int c = kt*4 + quad;                                     \
        _Pragma("unroll")                                                           \
        for (int rf=0; rf<4; ++rf)                                                  \
          av[u][rf] = *(const short8*)&(SRC)[xchunk(rf*16+col, c)];                 \
        bv[u][0] = *(const short8*)&(WPTR)[(((c << 8) + nbase + col) << 3)];        \
        bv[u][1] = *(const short8*)&(WPTR)[(((c << 8) + nbase + 16 + col) << 3)];   \
      }                                                                             \
      _Pragma("unroll")                                                             \
      for (int u=0; u<2; ++u){                                                      \
        _Pragma("unroll")                                                           \
        for (int rf=0; rf<4; ++rf){                                                 \
          Ya[rf][0] = MFMA16(av[u][rf], bv[u][0], Ya[rf][0]);                       \
          Ya[rf][1] = MFMA16(av[u][rf], bv[u][1], Ya[rf][1]);                       \
        }                                                                           \
      }                                                                             \
    }                                                                               \
  }

__global__ __launch_bounds__(512) void k_mega(
    const float* __restrict__ centers, const int* __restrict__ counts,
    const float* __restrict__ Wr, const float* __restrict__ br,
    const unsigned short* __restrict__ Wgrr, const float* __restrict__ bgr,
    const unsigned short* __restrict__ Wbc, const float* __restrict__ bbc,
    const float* __restrict__ alpha,
    const unsigned short* __restrict__ Wesa, const float* __restrict__ besa,
    const float* __restrict__ wmean, const float* __restrict__ bmu,
    const unsigned short* __restrict__ Aterm, float* __restrict__ outacc){
  __shared__ unsigned short Xa[64*256];    // rlf -> E=exp(resa); rows 56..63 pad/stats
  __shared__ unsigned short Yb[64*256];    // rlf_lin / resa
  float* hrSBp = (float*)&Xa[56*256];      // 512 f32 [jc*256+o]: 0.5/sum_i E
  float* gsbp  = (float*)&Xa[60*256];      // 64 f32 per row p: G = exp(gscore)
  float* hrSGp = (float*)&Xa[60*256+128];  // 2 f32 per jc: 0.5/sum_i G
  const int tid = threadIdx.x;
  const int wv = tid >> 6;          // 0..7 -> col slice
  const int lane = tid & 63, col = lane & 15, quad = lane >> 4;
  const int b = blockIdx.x / 14, jt = blockIdx.x - b*14;   // j = jt*2 + jc
  const int cb = counts[b];
  const int nbase = wv*32;

  float av_ = alpha[0];
  float tv = sigm(av_);
  float c1 = (1.f-tv)*(1.f-tv) + tv*tv;
  float c2 = 2.f*tv*(1.f-tv);

  int pis[4][4], pjs[4][4]; float pv[4][4];
  #pragma unroll
  for (int rf=0; rf<4; ++rf){
    #pragma unroll
    for (int r=0; r<4; ++r){
      int row = rf*16 + quad*4 + r;
      int i = row >> 1;
      pis[rf][r] = (i < 27) ? i : 27;
      pjs[rf][r] = jt*2 + (row & 1);
      pv[rf][r] = (row < 56 && i < cb && pjs[rf][r] < cb) ? 1.f : 0.f;
    }
  }
  // S0: rlf0[row] -> Xa ; pad rows = 0
  {
    int m = tid >> 3, sub = tid & 7;   // m 0..63, 32 cols each
    int i = m >> 1, j = jt*2 + (m & 1);
    bool valid = (m < 56);
    float mi = (valid && i < cb) ? 1.f : 0.f;
    float mj = (valid && j < cb) ? 1.f : 0.f;
    const float* ci = centers + (b*28 + (valid ? i : 0))*3;
    const float* cj = centers + (b*28 + j)*3;
    float dx = mi*ci[0] - mj*cj[0];
    float dy = mi*ci[1] - mj*cj[1];
    float dz = mi*ci[2] - mj*cj[2];
    for (int e = sub*32; e < sub*32 + 32; ++e){
      float v = valid ? (dx*Wr[e*3] + dy*Wr[e*3+1] + dz*Wr[e*3+2] + br[e]) : 0.f;
      Xa[xsw(m, e)] = f2b(v);
    }
  }
  __syncthreads();

  f32x4 Ya[4][2];
  #pragma unroll 1
  for (int l=0; l<3; ++l){
    // GEMM1: rlf(Xa) @ Wgr_r^T  -- then S2 writes Yb (no barrier in between)
    GEMM_TILE64(Xa, Wgrr);
    // S2: rlf_lin = Y + A_i + A_j + bgr -> Yb (bf16)
    const int lb = (l*7168 + b*28)*512;
    #pragma unroll
    for (int nt=0; nt<2; ++nt){
      int n = nbase + nt*16 + col;
      float bg = bgr[n];
      #pragma unroll
      for (int rf=0; rf<4; ++rf){
        #pragma unroll
        for (int r=0; r<4; ++r){
          float v = Ya[rf][nt][r] + bg
                  + b2f(Aterm[lb + pis[rf][r]*512 + n])
                  + b2f(Aterm[lb + pjs[rf][r]*512 + 256 + n]);
          Yb[xsw(rf*16 + quad*4 + r, n)] = f2b(v);
        }
      }
    }
    __syncthreads();   // Yb complete before GEMM2 reads it
    // GEMM2: rlf_lin(Yb) @ Wbc^T -- then S4 writes Xa (no barrier in between)
    GEMM_TILE64(Yb, Wbc);
    // S4: rlf = tanh(c1*rlf_lin + c2*(CP+bbc)) * pv -> Xa
    #pragma unroll
    for (int nt=0; nt<2; ++nt){
      int n = nbase + nt*16 + col;
      float bb = bbc[n];
      #pragma unroll
      for (int rf=0; rf<4; ++rf){
        #pragma unroll
        for (int r=0; r<4; ++r){
          int off = xsw(rf*16 + quad*4 + r, n);
          float rl = b2f(Yb[off]);
          float bez = c1*rl + c2*(Ya[rf][nt][r] + bb);
          Xa[off] = f2b(tanh_f(bez) * pv[rf][r]);
        }
      }
    }
    __syncthreads();   // Xa complete before next GEMM1; fences Yb readers vs next S2
  }
  // S5: resa = rlf(Xa) @ Wesa^T + besa -> v to Yb, E=exp(v) to Xa
  GEMM_TILE64(Xa, Wesa);
  __syncthreads();   // all GEMM reads of Xa(rlf) done before E overwrites it
  #pragma unroll
  for (int nt=0; nt<2; ++nt){
    int n = nbase + nt*16 + col;
    float be = besa[n];
    #pragma unroll
    for (int rf=0; rf<4; ++rf){
      #pragma unroll
      for (int r=0; r<4; ++r){
        int off = xsw(rf*16 + quad*4 + r, n);
        float v = Ya[rf][nt][r] + be;
        Yb[off] = f2b(v);            // resa value
        Xa[off] = f2b(__expf(v));    // E = exp(resa), exp done ONCE here
      }
    }
  }
  __syncthreads();
  // G[row] = exp(gscore) (reads Yb) + SB column sums of E (reads Xa) -- no exp
  {
    int m = tid >> 3, sub = tid & 7;   // 8 threads per row, 32 cols each
    if (m < 56){
      float s = 0.f;
      for (int e = sub*32; e < sub*32 + 32; ++e)
        s += b2f(Yb[xsw(m, e)]) * wmean[e];
      s += __shfl_xor(s, 1, 64);
      s += __shfl_xor(s, 2, 64);
      s += __shfl_xor(s, 4, 64);
      if (sub == 0)
        gsbp[m] = __expf(s + (bmu[0] + bmu[1] + bmu[2])*(1.f/3.f));
    }
  }
  {
    int jc = tid >> 8, o = tid & 255;  // all 512 threads
    float se = 0.f;
    for (int i=0;i<28;++i) se += b2f(Xa[xsw(i*2+jc, o)]);
    hrSBp[jc*256 + o] = 0.5f / se;
  }
  __syncthreads();
  if (tid < 2){
    int jc = tid;
    float se = 0.f;
    for (int i=0;i<28;++i) se += gsbp[i*2+jc];
    hrSGp[jc] = 0.5f / se;
  }
  __syncthreads();
  // output contribution of this block's 2 j's: one atomicAdd per (i,o), no exp
  for (int it = tid; it < 7168; it += 512){
    int i = it >> 8, o = it & 255;
    float s = 0.f;
    #pragma unroll
    for (int jc=0; jc<2; ++jc){
      int row = i*2 + jc;
      int off = xsw(row, o);
      float v = b2f(Yb[off]);
      float E = b2f(Xa[off]);
      float a = E*hrSBp[jc*256+o] + gsbp[row]*hrSGp[jc];
      s += a * v;
    }
    atomicAdd(&outacc[((size_t)b*28 + i)*256 + o], s);
  }
}

// ---------------- K5: mask + write f32 ----------------
__global__ __launch_bounds__(256) void k_out(const float* __restrict__ outacc,
                                             const int* __restrict__ counts,
                                             float* __restrict__ out){
  int b = blockIdx.x / 28, i = blockIdx.x - b*28, o = threadIdx.x;
  float acc = outacc[(size_t)blockIdx.x*256 + o];
  if (i >= counts[b]) acc = 0.f;
  out[(size_t)blockIdx.x*256 + o] = acc;
}

extern "C" void kernel_launch(void* const* d_in, const int* in_sizes, int n_in,
                              void* d_out, int out_size, void* d_ws, size_t ws_size,
                              hipStream_t stream){
  const float* centers = (const float*)d_in[0];
  const float* emb     = (const float*)d_in[1];
  const int*   counts  = (const int*)d_in[2];
  const float* Wr      = (const float*)d_in[3];
  const float* br      = (const float*)d_in[4];
  const float* Wih     = (const float*)d_in[5];
  const float* Whh     = (const float*)d_in[6];
  const float* bih     = (const float*)d_in[7];
  const float* bhh     = (const float*)d_in[8];
  const float* Wgr     = (const float*)d_in[9];
  const float* bgr     = (const float*)d_in[10];
  const float* Wbc     = (const float*)d_in[11];
  const float* bbc     = (const float*)d_in[12];
  const float* alpha   = (const float*)d_in[13];
  const float* Wesa    = (const float*)d_in[14];
  const float* besa    = (const float*)d_in[15];
  const float* Wmu     = (const float*)d_in[16];
  const float* bmu     = (const float*)d_in[17];
  // d_in[18], d_in[19] (Wlv, blv) are dead at eval time.

  // ws layout (42,075,136 bytes total):
  unsigned short* olf    = (unsigned short*)d_ws;                      // 3*7168*256 bf16 = 11,010,048 B
  unsigned short* At     = (unsigned short*)((char*)d_ws + 11010048);  // 3*7168*512 bf16 = 22,020,096 B
  unsigned short* zx     = At;                                         // 7168*1024 bf16 (aliases At)
  float*          outacc = (float*)((char*)d_ws + 33030144);           // 7168*256 f32 = 7,340,032 B
  unsigned short* wcv    = (unsigned short*)((char*)d_ws + 40370176);  // 851,968 bf16 = 1,703,936 B
  float*          wmean  = (float*)((char*)d_ws + 42074112);           // 256 f32 = 1,024 B
  unsigned short* cWih  = wcv;            // 262144 (N=1024)
  unsigned short* cWhh  = wcv + 262144;   // 262144 (N=1024)
  unsigned short* cWgri = wcv + 524288;   // 65536  (N=256)
  unsigned short* cWgrj = wcv + 589824;   // 65536  (N=256)
  unsigned short* cWgrr = wcv + 655360;   // 65536  (N=256)
  unsigned short* cWbc  = wcv + 720896;   // 65536  (N=256)
  unsigned short* cWesa = wcv + 786432;   // 65536  (N=256)
  float* outp = (float*)d_out;

  hipLaunchKernelGGL(k_repack7, dim3(3329), dim3(256), 0, stream,
                     Wih, Whh, Wgr, Wbc, Wesa, Wmu, wcv, wmean);

  hipLaunchKernelGGL(k_prep, dim3(7168), dim3(256), 0, stream, emb, counts, olf, outacc);
  // LSTM pass 1: olf0 -> olf1
  hipLaunchKernelGGL(k_xgemm, dim3(112), dim3(256), 0, stream, olf, cWih, zx);
  hipLaunchKernelGGL(k_rec,   dim3(16),  dim3(1024), 0, stream, zx, cWhh, bih, bhh, counts,
                     olf + (size_t)7168*256);
  // LSTM pass 2: olf1 -> olf2
  hipLaunchKernelGGL(k_xgemm, dim3(112), dim3(256), 0, stream, olf + (size_t)7168*256, cWih, zx);
  hipLaunchKernelGGL(k_rec,   dim3(16),  dim3(1024), 0, stream, zx, cWhh, bih, bhh, counts,
                     olf + (size_t)2*7168*256);
  hipLaunchKernelGGL(k_aterm, dim3(336), dim3(256), 0, stream, olf, cWgri, cWgrj, At);
  hipLaunchKernelGGL(k_mega,  dim3(3584), dim3(512), 0, stream,
                     centers, counts, Wr, br, cWgrr, bgr, cWbc, bbc, alpha,
                     cWesa, besa, wmean, bmu, At, outacc);
  hipLaunchKernelGGL(k_out,   dim3(7168), dim3(256), 0, stream, outacc, counts, outp);
}

// Round 20
// 1422.640 us; speedup vs baseline: 1.0312x; 1.0312x over previous
//
#include <hip/hip_runtime.h>

// ObjectMsgEncoder on MI355X. f32 I/O, bf16 MFMA internally (f32 accumulate).
// R19 -> R20: k_mega plateaued (~744us across 3 micro-attacks); attack the
// other ~723us:
//  * k_recat: fused kernel, blocks 0-15 = LSTM recurrence (16 CUs), blocks
//    16-43 = A-term GEMM for the pass's input layer on otherwise-IDLE CUs
//    (At_0 || rec1, At_1 || rec2). zx de-aliased from At (ws 49.4 MB).
//  * k_out eliminated: k_prep zeroes d_out; k_mega masks i<cb and atomicAdds
//    directly into d_out (skips masked atomics too).
//  * k_xgemm 112 -> 224 blocks (32-nt halves) for 2x CU coverage.

typedef __attribute__((ext_vector_type(8))) short short8;
typedef __attribute__((ext_vector_type(4))) float f32x4;

__device__ __forceinline__ float b2f(unsigned short u){
  union { unsigned int i; float f; } v; v.i = ((unsigned int)u) << 16; return v.f;
}
__device__ __forceinline__ unsigned short f2b(float f){
  union { float f; unsigned int i; } v; v.f = f;
  return (unsigned short)((v.i + 0x8000u) >> 16);   // round-half-up
}
__device__ __forceinline__ float sigm(float x){ return 1.f/(1.f+__expf(-x)); }
__device__ __forceinline__ float tanh_f(float x){ float e = __expf(2.f*x); return 1.f - 2.f/(e+1.f); }
// LDS swizzle: 8-element (16B) chunks, phys chunk = (c&24) | ((c^row)&7).
__device__ __forceinline__ int xsw(int row, int n){
  int c = n >> 3;
  int pc = (c & 24) | ((c ^ row) & 7);
  return row*256 + pc*8 + (n & 7);
}
__device__ __forceinline__ int xchunk(int row, int c){
  return row*256 + ((c & 24) | ((c ^ row) & 7))*8;
}

#define MFMA16(a,b,c) __builtin_amdgcn_mfma_f32_16x16x32_bf16((a),(b),(c),0,0,0)

// ---------------- K0: one-shot repack of all 7 weight blocks + wmean ----------------
__global__ __launch_bounds__(256) void k_repack7(const float* __restrict__ Wih,
                                                 const float* __restrict__ Whh,
                                                 const float* __restrict__ Wgr,
                                                 const float* __restrict__ Wbc,
                                                 const float* __restrict__ Wesa,
                                                 const float* __restrict__ Wmu,
                                                 unsigned short* __restrict__ wcv,
                                                 float* __restrict__ wmean){
  int i = blockIdx.x*256 + threadIdx.x;
  if (i >= 851968){                      // tail block: wmean
    int o = i - 851968;
    if (o < 256) wmean[o] = (Wmu[o] + Wmu[256+o] + Wmu[512+o]) * (1.f/3.f);
    return;
  }
  const float* s; int segbase, N, stride, off, local;
  if      (i < 262144){ s=Wih;  segbase=0;      N=1024; stride=256; off=0;   local=i; }
  else if (i < 524288){ s=Whh;  segbase=262144; N=1024; stride=256; off=0;   local=i-262144; }
  else if (i < 589824){ s=Wgr;  segbase=524288; N=256;  stride=768; off=0;   local=i-524288; }
  else if (i < 655360){ s=Wgr;  segbase=589824; N=256;  stride=768; off=256; local=i-589824; }
  else if (i < 720896){ s=Wgr;  segbase=655360; N=256;  stride=768; off=512; local=i-655360; }
  else if (i < 786432){ s=Wbc;  segbase=720896; N=256;  stride=256; off=0;   local=i-720896; }
  else                { s=Wesa; segbase=786432; N=256;  stride=256; off=0;   local=i-786432; }
  int n = local >> 8, k = local & 255;
  wcv[segbase + (((k >> 3)*N + n) << 3) + (k & 7)] = f2b(s[n*stride + off + k]);
}

// ---------------- K1: olf0 = emb * mask (f32 -> bf16) + zero out ----------------
__global__ __launch_bounds__(256) void k_prep(const float* __restrict__ emb,
                                              const int* __restrict__ counts,
                                              unsigned short* __restrict__ olf,
                                              float* __restrict__ out){
  int bs = blockIdx.x;            // b*28+s
  int b = bs / 28; int s = bs - b*28;
  int e = threadIdx.x;
  olf[(size_t)bs*256 + e] = (s < counts[b]) ? f2b(emb[(size_t)bs*256 + e]) : (unsigned short)0;
  out[(size_t)bs*256 + e] = 0.f;
}

// ---------------- K2a: zx = olf_l @ Wih^T  [7168,256]@[256,1024] -> bf16 ----------------
// 224 blocks: block handles 64 rows x one 32-nt half (2x CU coverage).
__global__ __launch_bounds__(256) void k_xgemm(const unsigned short* __restrict__ olf,
                                               const unsigned short* __restrict__ Wih,
                                               unsigned short* __restrict__ zx){
  const int tid = threadIdx.x;
  const int wid = tid >> 6, lane = tid & 63, col = lane & 15, quad = lane >> 4;
  const int m0 = (blockIdx.x >> 1)*64 + wid*16;
  const int nt0 = (blockIdx.x & 1)*32;
  short8 af[8];
  #pragma unroll
  for (int kt=0; kt<8; ++kt)
    af[kt] = *(const short8*)&olf[(size_t)(m0 + col)*256 + kt*32 + quad*8];
  #pragma unroll 4
  for (int nt=nt0; nt<nt0+32; ++nt){
    int n = nt*16 + col;
    f32x4 acc = (f32x4){0.f,0.f,0.f,0.f};
    #pragma unroll
    for (int kt=0; kt<8; ++kt){
      short8 bf = *(const short8*)&Wih[((((kt*4 + quad) << 10) + n) << 3)];
      acc = MFMA16(af[kt], bf, acc);
    }
    #pragma unroll
    for (int r=0; r<4; ++r)
      zx[(size_t)(m0 + quad*4 + r)*1024 + n] = f2b(acc[r]);
  }
}

// ---------------- K2b: FUSED recurrence + A-terms ----------------
// Blocks 0..15: LSTM recurrence (16 scenes each, 1024 thr, ping-pong h).
// Blocks 16..43: A-term GEMM for olf_at (the pass's INPUT layer) -> At_out.
//   (independent of the recurrence's writes; runs on otherwise-idle CUs)
__global__ __launch_bounds__(1024) void k_recat(const unsigned short* __restrict__ zx,
                                                const unsigned short* __restrict__ Whh,
                                                const float* __restrict__ bih,
                                                const float* __restrict__ bhh,
                                                const int* __restrict__ counts,
                                                unsigned short* __restrict__ olf_out,
                                                const unsigned short* __restrict__ olf_at,
                                                const unsigned short* __restrict__ Wgri,
                                                const unsigned short* __restrict__ Wgrj,
                                                unsigned short* __restrict__ At_out){
  __shared__ unsigned short Ab[2][16*264];   // used by rec blocks only
  const int tid = threadIdx.x;
  const int wv = tid >> 6, lane = tid & 63, col = lane & 15, quad = lane >> 4;

  if (blockIdx.x >= 16){
    // ---- aterm part: 16 waves x 16 rows = 256 rows per block ----
    const int m0 = (blockIdx.x - 16)*256 + wv*16;
    short8 af[8];
    #pragma unroll
    for (int kt=0; kt<8; ++kt)
      af[kt] = *(const short8*)&olf_at[(size_t)(m0 + col)*256 + kt*32 + quad*8];
    #pragma unroll 4
    for (int nt=0; nt<32; ++nt){
      const unsigned short* wb = (nt < 16) ? Wgri : Wgrj;
      int nn = (nt & 15)*16 + col;
      f32x4 acc = (f32x4){0.f,0.f,0.f,0.f};
      #pragma unroll
      for (int kt=0; kt<8; ++kt){
        short8 bf = *(const short8*)&wb[((((kt*4 + quad) << 8) + nn) << 3)];
        acc = MFMA16(af[kt], bf, acc);
      }
      #pragma unroll
      for (int r=0; r<4; ++r)
        At_out[(size_t)(m0 + quad*4 + r)*512 + nt*16 + col] = f2b(acc[r]);
    }
    return;
  }
  // ---- recurrence part ----
  const int sc0 = blockIdx.x * 16;
  const int u = wv*16 + col;
  float bz[4];
  #pragma unroll
  for (int g=0; g<4; ++g) bz[g] = bih[g*256+u] + bhh[g*256+u];
  int cnt4[4];
  #pragma unroll
  for (int r=0; r<4; ++r) cnt4[r] = counts[sc0 + quad*4 + r];

  float cst[4];
  #pragma unroll
  for (int r=0; r<4; ++r) cst[r] = 0.f;
  for (int i=tid; i<16*264; i+=1024) Ab[0][i] = 0;   // h0 = 0
  __syncthreads();

  for (int t=0; t<28; ++t){
    const int cur = t & 1, nxt = cur ^ 1;
    float zxv[4][4];
    #pragma unroll
    for (int g=0; g<4; ++g){
      #pragma unroll
      for (int r=0; r<4; ++r)
        zxv[g][r] = b2f(zx[((size_t)(sc0 + quad*4 + r)*28 + t)*1024 + g*256 + u]);
    }
    f32x4 acc[4];
    #pragma unroll
    for (int g=0; g<4; ++g) acc[g] = (f32x4){0.f,0.f,0.f,0.f};
    #pragma unroll
    for (int kt=0; kt<8; ++kt){
      short8 a = *(const short8*)&Ab[cur][col*264 + kt*32 + quad*8];
      #pragma unroll
      for (int g=0; g<4; ++g){
        short8 bf = *(const short8*)&Whh[((((kt*4 + quad) << 10) + g*256 + u) << 3)];
        acc[g] = MFMA16(a, bf, acc[g]);
      }
    }
    // no barrier: writes go to Ab[nxt], readers used Ab[cur]
    #pragma unroll
    for (int r=0; r<4; ++r){
      int s = quad*4 + r;
      float zi = acc[0][r] + zxv[0][r] + bz[0];
      float zf = acc[1][r] + zxv[1][r] + bz[1];
      float zg = acc[2][r] + zxv[2][r] + bz[2];
      float zo = acc[3][r] + zxv[3][r] + bz[3];
      float cc = sigm(zf)*cst[r] + sigm(zi)*tanh_f(zg);
      cst[r] = cc;
      float hh = sigm(zo)*tanh_f(cc);
      unsigned short hb = f2b(hh);
      Ab[nxt][s*264 + u] = hb;                              // raw h feeds recurrence
      olf_out[((size_t)(sc0+s)*28 + t)*256 + u] = (t < cnt4[r]) ? hb : (unsigned short)0;
    }
    __syncthreads();   // Ab[nxt] complete before step t+1 reads it
  }
}

// ---------------- K3: A-terms for ONE layer, [7168,256]@[256,512] -> bf16 ----------------
__global__ __launch_bounds__(256) void k_aterm(const unsigned short* __restrict__ olf,
                                               const unsigned short* __restrict__ Wgri,
                                               const unsigned short* __restrict__ Wgrj,
                                               unsigned short* __restrict__ Aout){
  const int tid = threadIdx.x;
  const int wid = tid >> 6, lane = tid & 63, col = lane & 15, quad = lane >> 4;
  const int m0 = blockIdx.x*64 + wid*16;
  short8 af[8];
  #pragma unroll
  for (int kt=0; kt<8; ++kt)
    af[kt] = *(const short8*)&olf[(size_t)(m0 + col)*256 + kt*32 + quad*8];
  #pragma unroll 4
  for (int nt=0; nt<32; ++nt){
    const unsigned short* wb = (nt < 16) ? Wgri : Wgrj;
    int nn = (nt & 15)*16 + col;
    f32x4 acc = (f32x4){0.f,0.f,0.f,0.f};
    #pragma unroll
    for (int kt=0; kt<8; ++kt){
      short8 bf = *(const short8*)&wb[((((kt*4 + quad) << 8) + nn) << 3)];
      acc = MFMA16(af[kt], bf, acc);
    }
    #pragma unroll
    for (int r=0; r<4; ++r)
      Aout[(size_t)(m0 + quad*4 + r)*512 + nt*16 + col] = f2b(acc[r]);
  }
}

// ---------------- K4: fused per-(scene, j-pair), ping-pong LDS ----------------
#define GEMM_TILE64(SRC, WPTR)                                                      \
  {                                                                                 \
    _Pragma("unroll")                                                               \
    for (int rf=0; rf<4; ++rf){ Ya[rf][0]=(f32x4){0.f,0.f,0.f,0.f};                 \
                                Ya[rf][1]=(f32x4){0.f,0.f,0.f,0.f}; }               \
    _Pragma("unroll 1")                                                             \
    for (int kc=0; kc<4; ++kc){                                                     \
      short8 av[2][4], bv[2][2];                                                    \
      _Pragma("unroll")                                                             \
      for (int u=0; u<2; ++u){                                                      \
        int kt = kc*2 + u; int c = kt*4 + quad;                                     \
        _Pragma("unroll")                                                           \
        for (int rf=0; rf<4; ++rf)                                                  \
          av[u][rf] = *(const short8*)&(SRC)[xchunk(rf*16+col, c)];                 \
        bv[u][0] = *(const short8*)&(WPTR)[(((c << 8) + nbase + col) << 3)];        \
        bv[u][1] = *(const short8*)&(WPTR)[(((c << 8) + nbase + 16 + col) << 3)];   \
      }                                                                             \
      _Pragma("unroll")                                                             \
      for (int u=0; u<2; ++u){                                                      \
        _Pragma("unroll")                                                           \
        for (int rf=0; rf<4; ++rf){                                                 \
          Ya[rf][0] = MFMA16(av[u][rf], bv[u][0], Ya[rf][0]);                       \
          Ya[rf][1] = MFMA16(av[u][rf], bv[u][1], Ya[rf][1]);                       \
        }                                                                           \
      }                                                                             \
    }                                                                               \
  }

__global__ __launch_bounds__(512) void k_mega(
    const float* __restrict__ centers, const int* __restrict__ counts,
    const float* __restrict__ Wr, const float* __restrict__ br,
    const unsigned short* __restrict__ Wgrr, const float* __restrict__ bgr,
    const unsigned short* __restrict__ Wbc, const float* __restrict__ bbc,
    const float* __restrict__ alpha,
    const unsigned short* __restrict__ Wesa, const float* __restrict__ besa,
    const float* __restrict__ wmean, const float* __restrict__ bmu,
    const unsigned short* __restrict__ Aterm, float* __restrict__ out){
  __shared__ unsigned short Xa[64*256];    // rlf -> E=exp(resa); rows 56..63 pad/stats
  __shared__ unsigned short Yb[64*256];    // rlf_lin / resa
  float* hrSBp = (float*)&Xa[56*256];      // 512 f32 [jc*256+o]: 0.5/sum_i E
  float* gsbp  = (float*)&Xa[60*256];      // 64 f32 per row p: G = exp(gscore)
  float* hrSGp = (float*)&Xa[60*256+128];  // 2 f32 per jc: 0.5/sum_i G
  const int tid = threadIdx.x;
  const int wv = tid >> 6;          // 0..7 -> col slice
  const int lane = tid & 63, col = lane & 15, quad = lane >> 4;
  const int b = blockIdx.x / 14, jt = blockIdx.x - b*14;   // j = jt*2 + jc
  const int cb = counts[b];
  const int nbase = wv*32;

  float av_ = alpha[0];
  float tv = sigm(av_);
  float c1 = (1.f-tv)*(1.f-tv) + tv*tv;
  float c2 = 2.f*tv*(1.f-tv);

  int pis[4][4], pjs[4][4]; float pv[4][4];
  #pragma unroll
  for (int rf=0; rf<4; ++rf){
    #pragma unroll
    for (int r=0; r<4; ++r){
      int row = rf*16 + quad*4 + r;
      int i = row >> 1;
      pis[rf][r] = (i < 27) ? i : 27;
      pjs[rf][r] = jt*2 + (row & 1);
      pv[rf][r] = (row < 56 && i < cb && pjs[rf][r] < cb) ? 1.f : 0.f;
    }
  }
  // S0: rlf0[row] -> Xa ; pad rows = 0
  {
    int m = tid >> 3, sub = tid & 7;   // m 0..63, 32 cols each
    int i = m >> 1, j = jt*2 + (m & 1);
    bool valid = (m < 56);
    float mi = (valid && i < cb) ? 1.f : 0.f;
    float mj = (valid && j < cb) ? 1.f : 0.f;
    const float* ci = centers + (b*28 + (valid ? i : 0))*3;
    const float* cj = centers + (b*28 + j)*3;
    float dx = mi*ci[0] - mj*cj[0];
    float dy = mi*ci[1] - mj*cj[1];
    float dz = mi*ci[2] - mj*cj[2];
    for (int e = sub*32; e < sub*32 + 32; ++e){
      float v = valid ? (dx*Wr[e*3] + dy*Wr[e*3+1] + dz*Wr[e*3+2] + br[e]) : 0.f;
      Xa[xsw(m, e)] = f2b(v);
    }
  }
  __syncthreads();

  f32x4 Ya[4][2];
  #pragma unroll 1
  for (int l=0; l<3; ++l){
    // GEMM1: rlf(Xa) @ Wgr_r^T  -- then S2 writes Yb (no barrier in between)
    GEMM_TILE64(Xa, Wgrr);
    // S2: rlf_lin = Y + A_i + A_j + bgr -> Yb (bf16)
    const int lb = (l*7168 + b*28)*512;
    #pragma unroll
    for (int nt=0; nt<2; ++nt){
      int n = nbase + nt*16 + col;
      float bg = bgr[n];
      #pragma unroll
      for (int rf=0; rf<4; ++rf){
        #pragma unroll
        for (int r=0; r<4; ++r){
          float v = Ya[rf][nt][r] + bg
                  + b2f(Aterm[lb + pis[rf][r]*512 + n])
                  + b2f(Aterm[lb + pjs[rf][r]*512 + 256 + n]);
          Yb[xsw(rf*16 + quad*4 + r, n)] = f2b(v);
        }
      }
    }
    __syncthreads();   // Yb complete before GEMM2 reads it
    // GEMM2: rlf_lin(Yb) @ Wbc^T -- then S4 writes Xa (no barrier in between)
    GEMM_TILE64(Yb, Wbc);
    // S4: rlf = tanh(c1*rlf_lin + c2*(CP+bbc)) * pv -> Xa
    #pragma unroll
    for (int nt=0; nt<2; ++nt){
      int n = nbase + nt*16 + col;
      float bb = bbc[n];
      #pragma unroll
      for (int rf=0; rf<4; ++rf){
        #pragma unroll
        for (int r=0; r<4; ++r){
          int off = xsw(rf*16 + quad*4 + r, n);
          float rl = b2f(Yb[off]);
          float bez = c1*rl + c2*(Ya[rf][nt][r] + bb);
          Xa[off] = f2b(tanh_f(bez) * pv[rf][r]);
        }
      }
    }
    __syncthreads();   // Xa complete before next GEMM1; fences Yb readers vs next S2
  }
  // S5: resa = rlf(Xa) @ Wesa^T + besa -> v to Yb, E=exp(v) to Xa
  GEMM_TILE64(Xa, Wesa);
  __syncthreads();   // all GEMM reads of Xa(rlf) done before E overwrites it
  #pragma unroll
  for (int nt=0; nt<2; ++nt){
    int n = nbase + nt*16 + col;
    float be = besa[n];
    #pragma unroll
    for (int rf=0; rf<4; ++rf){
      #pragma unroll
      for (int r=0; r<4; ++r){
        int off = xsw(rf*16 + quad*4 + r, n);
        float v = Ya[rf][nt][r] + be;
        Yb[off] = f2b(v);            // resa value
        Xa[off] = f2b(__expf(v));    // E = exp(resa), once
      }
    }
  }
  __syncthreads();
  // G[row] = exp(gscore) (reads Yb) + SB column sums of E (reads Xa)
  {
    int m = tid >> 3, sub = tid & 7;   // 8 threads per row, 32 cols each
    if (m < 56){
      float s = 0.f;
      for (int e = sub*32; e < sub*32 + 32; ++e)
        s += b2f(Yb[xsw(m, e)]) * wmean[e];
      s += __shfl_xor(s, 1, 64);
      s += __shfl_xor(s, 2, 64);
      s += __shfl_xor(s, 4, 64);
      if (sub == 0)
        gsbp[m] = __expf(s + (bmu[0] + bmu[1] + bmu[2])*(1.f/3.f));
    }
  }
  {
    int jc = tid >> 8, o = tid & 255;  // all 512 threads
    float se = 0.f;
    for (int i=0;i<28;++i) se += b2f(Xa[xsw(i*2+jc, o)]);
    hrSBp[jc*256 + o] = 0.5f / se;
  }
  __syncthreads();
  if (tid < 2){
    int jc = tid;
    float se = 0.f;
    for (int i=0;i<28;++i) se += gsbp[i*2+jc];
    hrSGp[jc] = 0.5f / se;
  }
  __syncthreads();
  // masked output: atomicAdd straight into d_out (zeroed by k_prep)
  for (int it = tid; it < 7168; it += 512){
    int i = it >> 8, o = it & 255;
    if (i < cb){
      float s = 0.f;
      #pragma unroll
      for (int jc=0; jc<2; ++jc){
        int row = i*2 + jc;
        int off = xsw(row, o);
        float v = b2f(Yb[off]);
        float E = b2f(Xa[off]);
        float a = E*hrSBp[jc*256+o] + gsbp[row]*hrSGp[jc];
        s += a * v;
      }
      atomicAdd(&out[((size_t)b*28 + i)*256 + o], s);
    }
  }
}

extern "C" void kernel_launch(void* const* d_in, const int* in_sizes, int n_in,
                              void* d_out, int out_size, void* d_ws, size_t ws_size,
                              hipStream_t stream){
  const float* centers = (const float*)d_in[0];
  const float* emb     = (const float*)d_in[1];
  const int*   counts  = (const int*)d_in[2];
  const float* Wr      = (const float*)d_in[3];
  const float* br      = (const float*)d_in[4];
  const float* Wih     = (const float*)d_in[5];
  const float* Whh     = (const float*)d_in[6];
  const float* bih     = (const float*)d_in[7];
  const float* bhh     = (const float*)d_in[8];
  const float* Wgr     = (const float*)d_in[9];
  const float* bgr     = (const float*)d_in[10];
  const float* Wbc     = (const float*)d_in[11];
  const float* bbc     = (const float*)d_in[12];
  const float* alpha   = (const float*)d_in[13];
  const float* Wesa    = (const float*)d_in[14];
  const float* besa    = (const float*)d_in[15];
  const float* Wmu     = (const float*)d_in[16];
  const float* bmu     = (const float*)d_in[17];
  // d_in[18], d_in[19] (Wlv, blv) are dead at eval time.

  // ws layout (49,415,168 bytes total):
  unsigned short* olf   = (unsigned short*)d_ws;                      // 3*7168*256 bf16 = 11,010,048 B
  unsigned short* At    = (unsigned short*)((char*)d_ws + 11010048);  // 3*7168*512 bf16 = 22,020,096 B
  unsigned short* zx    = (unsigned short*)((char*)d_ws + 33030144);  // 7168*1024 bf16 = 14,680,064 B (de-aliased)
  unsigned short* wcv   = (unsigned short*)((char*)d_ws + 47710208);  // 851,968 bf16 = 1,703,936 B
  float*          wmean = (float*)((char*)d_ws + 49414144);           // 256 f32
  unsigned short* cWih  = wcv;            // 262144 (N=1024)
  unsigned short* cWhh  = wcv + 262144;   // 262144 (N=1024)
  unsigned short* cWgri = wcv + 524288;   // 65536  (N=256)
  unsigned short* cWgrj = wcv + 589824;   // 65536  (N=256)
  unsigned short* cWgrr = wcv + 655360;   // 65536  (N=256)
  unsigned short* cWbc  = wcv + 720896;   // 65536  (N=256)
  unsigned short* cWesa = wcv + 786432;   // 65536  (N=256)
  float* outp = (float*)d_out;

  unsigned short* olf1 = olf + (size_t)7168*256;
  unsigned short* olf2 = olf + (size_t)2*7168*256;
  unsigned short* At1  = At  + (size_t)7168*512;
  unsigned short* At2  = At  + (size_t)2*7168*512;

  hipLaunchKernelGGL(k_repack7, dim3(3329), dim3(256), 0, stream,
                     Wih, Whh, Wgr, Wbc, Wesa, Wmu, wcv, wmean);
  hipLaunchKernelGGL(k_prep, dim3(7168), dim3(256), 0, stream, emb, counts, olf, outp);
  // LSTM pass 1 (olf0 -> olf1) fused with A-terms layer 0 (olf0 -> At0)
  hipLaunchKernelGGL(k_xgemm, dim3(224), dim3(256), 0, stream, olf, cWih, zx);
  hipLaunchKernelGGL(k_recat, dim3(44), dim3(1024), 0, stream,
                     zx, cWhh, bih, bhh, counts, olf1, olf, cWgri, cWgrj, At);
  // LSTM pass 2 (olf1 -> olf2) fused with A-terms layer 1 (olf1 -> At1)
  hipLaunchKernelGGL(k_xgemm, dim3(224), dim3(256), 0, stream, olf1, cWih, zx);
  hipLaunchKernelGGL(k_recat, dim3(44), dim3(1024), 0, stream,
                     zx, cWhh, bih, bhh, counts, olf2, olf1, cWgri, cWgrj, At1);
  // A-terms layer 2 (olf2 -> At2)
  hipLaunchKernelGGL(k_aterm, dim3(112), dim3(256), 0, stream, olf2, cWgri, cWgrj, At2);
  hipLaunchKernelGGL(k_mega,  dim3(3584), dim3(512), 0, stream,
                     centers, counts, Wr, br, cWgrr, bgr, cWbc, bbc, alpha,
                     cWesa, besa, wmean, bmu, At, outp);
}

// Round 21
// 1332.273 us; speedup vs baseline: 1.1011x; 1.0678x over previous
//
#include <hip/hip_runtime.h>

// ObjectMsgEncoder on MI355X. f32 I/O, bf16 MFMA internally (f32 accumulate).
// R20 -> R21: At prefetch in k_mega. S2's 64 scattered At loads/thread were
// issued AFTER GEMM1 (3 layers x ~1-1.5K cyc exposed L2/L3 latency). Now they
// load into registers BEFORE GEMM1 (independent of its inputs) and S2 consumes
// registers. VGPR grows ~64 but k_mega is LDS-capped at 1 block/CU (65KB), so
// occupancy is unchanged (8 waves needs <=256 VGPR). All else identical to R20.

typedef __attribute__((ext_vector_type(8))) short short8;
typedef __attribute__((ext_vector_type(4))) float f32x4;

__device__ __forceinline__ float b2f(unsigned short u){
  union { unsigned int i; float f; } v; v.i = ((unsigned int)u) << 16; return v.f;
}
__device__ __forceinline__ unsigned short f2b(float f){
  union { float f; unsigned int i; } v; v.f = f;
  return (unsigned short)((v.i + 0x8000u) >> 16);   // round-half-up
}
__device__ __forceinline__ float sigm(float x){ return 1.f/(1.f+__expf(-x)); }
__device__ __forceinline__ float tanh_f(float x){ float e = __expf(2.f*x); return 1.f - 2.f/(e+1.f); }
// LDS swizzle: 8-element (16B) chunks, phys chunk = (c&24) | ((c^row)&7).
__device__ __forceinline__ int xsw(int row, int n){
  int c = n >> 3;
  int pc = (c & 24) | ((c ^ row) & 7);
  return row*256 + pc*8 + (n & 7);
}
__device__ __forceinline__ int xchunk(int row, int c){
  return row*256 + ((c & 24) | ((c ^ row) & 7))*8;
}

#define MFMA16(a,b,c) __builtin_amdgcn_mfma_f32_16x16x32_bf16((a),(b),(c),0,0,0)

// ---------------- K0: one-shot repack of all 7 weight blocks + wmean ----------------
__global__ __launch_bounds__(256) void k_repack7(const float* __restrict__ Wih,
                                                 const float* __restrict__ Whh,
                                                 const float* __restrict__ Wgr,
                                                 const float* __restrict__ Wbc,
                                                 const float* __restrict__ Wesa,
                                                 const float* __restrict__ Wmu,
                                                 unsigned short* __restrict__ wcv,
                                                 float* __restrict__ wmean){
  int i = blockIdx.x*256 + threadIdx.x;
  if (i >= 851968){                      // tail block: wmean
    int o = i - 851968;
    if (o < 256) wmean[o] = (Wmu[o] + Wmu[256+o] + Wmu[512+o]) * (1.f/3.f);
    return;
  }
  const float* s; int segbase, N, stride, off, local;
  if      (i < 262144){ s=Wih;  segbase=0;      N=1024; stride=256; off=0;   local=i; }
  else if (i < 524288){ s=Whh;  segbase=262144; N=1024; stride=256; off=0;   local=i-262144; }
  else if (i < 589824){ s=Wgr;  segbase=524288; N=256;  stride=768; off=0;   local=i-524288; }
  else if (i < 655360){ s=Wgr;  segbase=589824; N=256;  stride=768; off=256; local=i-589824; }
  else if (i < 720896){ s=Wgr;  segbase=655360; N=256;  stride=768; off=512; local=i-655360; }
  else if (i < 786432){ s=Wbc;  segbase=720896; N=256;  stride=256; off=0;   local=i-720896; }
  else                { s=Wesa; segbase=786432; N=256;  stride=256; off=0;   local=i-786432; }
  int n = local >> 8, k = local & 255;
  wcv[segbase + (((k >> 3)*N + n) << 3) + (k & 7)] = f2b(s[n*stride + off + k]);
}

// ---------------- K1: olf0 = emb * mask (f32 -> bf16) + zero out ----------------
__global__ __launch_bounds__(256) void k_prep(const float* __restrict__ emb,
                                              const int* __restrict__ counts,
                                              unsigned short* __restrict__ olf,
                                              float* __restrict__ out){
  int bs = blockIdx.x;            // b*28+s
  int b = bs / 28; int s = bs - b*28;
  int e = threadIdx.x;
  olf[(size_t)bs*256 + e] = (s < counts[b]) ? f2b(emb[(size_t)bs*256 + e]) : (unsigned short)0;
  out[(size_t)bs*256 + e] = 0.f;
}

// ---------------- K2a: zx = olf_l @ Wih^T  [7168,256]@[256,1024] -> bf16 ----------------
__global__ __launch_bounds__(256) void k_xgemm(const unsigned short* __restrict__ olf,
                                               const unsigned short* __restrict__ Wih,
                                               unsigned short* __restrict__ zx){
  const int tid = threadIdx.x;
  const int wid = tid >> 6, lane = tid & 63, col = lane & 15, quad = lane >> 4;
  const int m0 = (blockIdx.x >> 1)*64 + wid*16;
  const int nt0 = (blockIdx.x & 1)*32;
  short8 af[8];
  #pragma unroll
  for (int kt=0; kt<8; ++kt)
    af[kt] = *(const short8*)&olf[(size_t)(m0 + col)*256 + kt*32 + quad*8];
  #pragma unroll 4
  for (int nt=nt0; nt<nt0+32; ++nt){
    int n = nt*16 + col;
    f32x4 acc = (f32x4){0.f,0.f,0.f,0.f};
    #pragma unroll
    for (int kt=0; kt<8; ++kt){
      short8 bf = *(const short8*)&Wih[((((kt*4 + quad) << 10) + n) << 3)];
      acc = MFMA16(af[kt], bf, acc);
    }
    #pragma unroll
    for (int r=0; r<4; ++r)
      zx[(size_t)(m0 + quad*4 + r)*1024 + n] = f2b(acc[r]);
  }
}

// ---------------- K2b: FUSED recurrence + A-terms ----------------
__global__ __launch_bounds__(1024) void k_recat(const unsigned short* __restrict__ zx,
                                                const unsigned short* __restrict__ Whh,
                                                const float* __restrict__ bih,
                                                const float* __restrict__ bhh,
                                                const int* __restrict__ counts,
                                                unsigned short* __restrict__ olf_out,
                                                const unsigned short* __restrict__ olf_at,
                                                const unsigned short* __restrict__ Wgri,
                                                const unsigned short* __restrict__ Wgrj,
                                                unsigned short* __restrict__ At_out){
  __shared__ unsigned short Ab[2][16*264];   // used by rec blocks only
  const int tid = threadIdx.x;
  const int wv = tid >> 6, lane = tid & 63, col = lane & 15, quad = lane >> 4;

  if (blockIdx.x >= 16){
    // ---- aterm part: 16 waves x 16 rows = 256 rows per block ----
    const int m0 = (blockIdx.x - 16)*256 + wv*16;
    short8 af[8];
    #pragma unroll
    for (int kt=0; kt<8; ++kt)
      af[kt] = *(const short8*)&olf_at[(size_t)(m0 + col)*256 + kt*32 + quad*8];
    #pragma unroll 4
    for (int nt=0; nt<32; ++nt){
      const unsigned short* wb = (nt < 16) ? Wgri : Wgrj;
      int nn = (nt & 15)*16 + col;
      f32x4 acc = (f32x4){0.f,0.f,0.f,0.f};
      #pragma unroll
      for (int kt=0; kt<8; ++kt){
        short8 bf = *(const short8*)&wb[((((kt*4 + quad) << 8) + nn) << 3)];
        acc = MFMA16(af[kt], bf, acc);
      }
      #pragma unroll
      for (int r=0; r<4; ++r)
        At_out[(size_t)(m0 + quad*4 + r)*512 + nt*16 + col] = f2b(acc[r]);
    }
    return;
  }
  // ---- recurrence part ----
  const int sc0 = blockIdx.x * 16;
  const int u = wv*16 + col;
  float bz[4];
  #pragma unroll
  for (int g=0; g<4; ++g) bz[g] = bih[g*256+u] + bhh[g*256+u];
  int cnt4[4];
  #pragma unroll
  for (int r=0; r<4; ++r) cnt4[r] = counts[sc0 + quad*4 + r];

  float cst[4];
  #pragma unroll
  for (int r=0; r<4; ++r) cst[r] = 0.f;
  for (int i=tid; i<16*264; i+=1024) Ab[0][i] = 0;   // h0 = 0
  __syncthreads();

  for (int t=0; t<28; ++t){
    const int cur = t & 1, nxt = cur ^ 1;
    float zxv[4][4];
    #pragma unroll
    for (int g=0; g<4; ++g){
      #pragma unroll
      for (int r=0; r<4; ++r)
        zxv[g][r] = b2f(zx[((size_t)(sc0 + quad*4 + r)*28 + t)*1024 + g*256 + u]);
    }
    f32x4 acc[4];
    #pragma unroll
    for (int g=0; g<4; ++g) acc[g] = (f32x4){0.f,0.f,0.f,0.f};
    #pragma unroll
    for (int kt=0; kt<8; ++kt){
      short8 a = *(const short8*)&Ab[cur][col*264 + kt*32 + quad*8];
      #pragma unroll
      for (int g=0; g<4; ++g){
        short8 bf = *(const short8*)&Whh[((((kt*4 + quad) << 10) + g*256 + u) << 3)];
        acc[g] = MFMA16(a, bf, acc[g]);
      }
    }
    // no barrier: writes go to Ab[nxt], readers used Ab[cur]
    #pragma unroll
    for (int r=0; r<4; ++r){
      int s = quad*4 + r;
      float zi = acc[0][r] + zxv[0][r] + bz[0];
      float zf = acc[1][r] + zxv[1][r] + bz[1];
      float zg = acc[2][r] + zxv[2][r] + bz[2];
      float zo = acc[3][r] + zxv[3][r] + bz[3];
      float cc = sigm(zf)*cst[r] + sigm(zi)*tanh_f(zg);
      cst[r] = cc;
      float hh = sigm(zo)*tanh_f(cc);
      unsigned short hb = f2b(hh);
      Ab[nxt][s*264 + u] = hb;                              // raw h feeds recurrence
      olf_out[((size_t)(sc0+s)*28 + t)*256 + u] = (t < cnt4[r]) ? hb : (unsigned short)0;
    }
    __syncthreads();   // Ab[nxt] complete before step t+1 reads it
  }
}

// ---------------- K3: A-terms for ONE layer, [7168,256]@[256,512] -> bf16 ----------------
__global__ __launch_bounds__(256) void k_aterm(const unsigned short* __restrict__ olf,
                                               const unsigned short* __restrict__ Wgri,
                                               const unsigned short* __restrict__ Wgrj,
                                               unsigned short* __restrict__ Aout){
  const int tid = threadIdx.x;
  const int wid = tid >> 6, lane = tid & 63, col = lane & 15, quad = lane >> 4;
  const int m0 = blockIdx.x*64 + wid*16;
  short8 af[8];
  #pragma unroll
  for (int kt=0; kt<8; ++kt)
    af[kt] = *(const short8*)&olf[(size_t)(m0 + col)*256 + kt*32 + quad*8];
  #pragma unroll 4
  for (int nt=0; nt<32; ++nt){
    const unsigned short* wb = (nt < 16) ? Wgri : Wgrj;
    int nn = (nt & 15)*16 + col;
    f32x4 acc = (f32x4){0.f,0.f,0.f,0.f};
    #pragma unroll
    for (int kt=0; kt<8; ++kt){
      short8 bf = *(const short8*)&wb[((((kt*4 + quad) << 8) + nn) << 3)];
      acc = MFMA16(af[kt], bf, acc);
    }
    #pragma unroll
    for (int r=0; r<4; ++r)
      Aout[(size_t)(m0 + quad*4 + r)*512 + nt*16 + col] = f2b(acc[r]);
  }
}

// ---------------- K4: fused per-(scene, j-pair), ping-pong LDS + At prefetch ----------------
#define GEMM_TILE64(SRC, WPTR)                                                      \
  {                                                                                 \
    _Pragma("unroll")                                                               \
    for (int rf=0; rf<4; ++rf){ Ya[rf][0]=(f32x4){0.f,0.f,0.f,0.f};                 \
                                Ya[rf][1]=(f32x4){0.f,0.f,0.f,0.f}; }               \
    _Pragma("unroll 1")                                                             \
    for (int kc=0; kc<4; ++kc){                                                     \
      short8 av[2][4], bv[2][2];                                                    \
      _Pragma("unroll")                                                             \
      for (int u=0; u<2; ++u){                                                      \
        int kt = kc*2 + u; int c = kt*4 + quad;                                     \
        _Pragma("unroll")                                                           \
        for (int rf=0; rf<4; ++rf)                                                  \
          av[u][rf] = *(const short8*)&(SRC)[xchunk(rf*16+col, c)];                 \
        bv[u][0] = *(const short8*)&(WPTR)[(((c << 8) + nbase + col) << 3)];        \
        bv[u][1] = *(const short8*)&(WPTR)[(((c << 8) + nbase + 16 + col) << 3)];   \
      }                                                                             \
      _Pragma("unroll")                                                             \
      for (int u=0; u<2; ++u){                                                      \
        _Pragma("unroll")                                                           \
        for (int rf=0; rf<4; ++rf){                                                 \
          Ya[rf][0] = MFMA16(av[u][rf], bv[u][0], Ya[rf][0]);                       \
          Ya[rf][1] = MFMA16(av[u][rf], bv[u][1], Ya[rf][1]);                       \
        }                                                                           \
      }                                                                             \
    }                                                                               \
  }

__global__ __launch_bounds__(512) void k_mega(
    const float* __restrict__ centers, const int* __restrict__ counts,
    const float* __restrict__ Wr, const float* __restrict__ br,
    const unsigned short* __restrict__ Wgrr, const float* __restrict__ bgr,
    const unsigned short* __restrict__ Wbc, const float* __restrict__ bbc,
    const float* __restrict__ alpha,
    const unsigned short* __restrict__ Wesa, const float* __restrict__ besa,
    const float* __restrict__ wmean, const float* __restrict__ bmu,
    const unsigned short* __restrict__ Aterm, float* __restrict__ out){
  __shared__ unsigned short Xa[64*256];    // rlf -> E=exp(resa); rows 56..63 pad/stats
  __shared__ unsigned short Yb[64*256];    // rlf_lin / resa
  float* hrSBp = (float*)&Xa[56*256];      // 512 f32 [jc*256+o]: 0.5/sum_i E
  float* gsbp  = (float*)&Xa[60*256];      // 64 f32 per row p: G = exp(gscore)
  float* hrSGp = (float*)&Xa[60*256+128];  // 2 f32 per jc: 0.5/sum_i G
  const int tid = threadIdx.x;
  const int wv = tid >> 6;          // 0..7 -> col slice
  const int lane = tid & 63, col = lane & 15, quad = lane >> 4;
  const int b = blockIdx.x / 14, jt = blockIdx.x - b*14;   // j = jt*2 + jc
  const int cb = counts[b];
  const int nbase = wv*32;

  float av_ = alpha[0];
  float tv = sigm(av_);
  float c1 = (1.f-tv)*(1.f-tv) + tv*tv;
  float c2 = 2.f*tv*(1.f-tv);

  int pis[4][4], pjs[4][4]; float pv[4][4];
  #pragma unroll
  for (int rf=0; rf<4; ++rf){
    #pragma unroll
    for (int r=0; r<4; ++r){
      int row = rf*16 + quad*4 + r;
      int i = row >> 1;
      pis[rf][r] = (i < 27) ? i : 27;
      pjs[rf][r] = jt*2 + (row & 1);
      pv[rf][r] = (row < 56 && i < cb && pjs[rf][r] < cb) ? 1.f : 0.f;
    }
  }
  // S0: rlf0[row] -> Xa ; pad rows = 0
  {
    int m = tid >> 3, sub = tid & 7;   // m 0..63, 32 cols each
    int i = m >> 1, j = jt*2 + (m & 1);
    bool valid = (m < 56);
    float mi = (valid && i < cb) ? 1.f : 0.f;
    float mj = (valid && j < cb) ? 1.f : 0.f;
    const float* ci = centers + (b*28 + (valid ? i : 0))*3;
    const float* cj = centers + (b*28 + j)*3;
    float dx = mi*ci[0] - mj*cj[0];
    float dy = mi*ci[1] - mj*cj[1];
    float dz = mi*ci[2] - mj*cj[2];
    for (int e = sub*32; e < sub*32 + 32; ++e){
      float v = valid ? (dx*Wr[e*3] + dy*Wr[e*3+1] + dz*Wr[e*3+2] + br[e]) : 0.f;
      Xa[xsw(m, e)] = f2b(v);
    }
  }
  __syncthreads();

  f32x4 Ya[4][2];
  #pragma unroll 1
  for (int l=0; l<3; ++l){
    // At PREFETCH for this layer's S2 -- issued BEFORE GEMM1 (independent of Xa);
    // the waitcnt lands between GEMM1's end and S2's first use.
    const int lb = (l*7168 + b*28)*512;
    unsigned short rAi[2][4][4], rAj[2][4][4];
    #pragma unroll
    for (int nt=0; nt<2; ++nt){
      int n = nbase + nt*16 + col;
      #pragma unroll
      for (int rf=0; rf<4; ++rf){
        #pragma unroll
        for (int r=0; r<4; ++r){
          rAi[nt][rf][r] = Aterm[lb + pis[rf][r]*512 + n];
          rAj[nt][rf][r] = Aterm[lb + pjs[rf][r]*512 + 256 + n];
        }
      }
    }
    // GEMM1: rlf(Xa) @ Wgr_r^T  -- then S2 writes Yb (no barrier in between)
    GEMM_TILE64(Xa, Wgrr);
    // S2: rlf_lin = Y + A_i + A_j + bgr -> Yb (bf16), A-terms from registers
    #pragma unroll
    for (int nt=0; nt<2; ++nt){
      int n = nbase + nt*16 + col;
      float bg = bgr[n];
      #pragma unroll
      for (int rf=0; rf<4; ++rf){
        #pragma unroll
        for (int r=0; r<4; ++r){
          float v = Ya[rf][nt][r] + bg + b2f(rAi[nt][rf][r]) + b2f(rAj[nt][rf][r]);
          Yb[xsw(rf*16 + quad*4 + r, n)] = f2b(v);
        }
      }
    }
    __syncthreads();   // Yb complete before GEMM2 reads it
    // GEMM2: rlf_lin(Yb) @ Wbc^T -- then S4 writes Xa (no barrier in between)
    GEMM_TILE64(Yb, Wbc);
    // S4: rlf = tanh(c1*rlf_lin + c2*(CP+bbc)) * pv -> Xa
    #pragma unroll
    for (int nt=0; nt<2; ++nt){
      int n = nbase + nt*16 + col;
      float bb = bbc[n];
      #pragma unroll
      for (int rf=0; rf<4; ++rf){
        #pragma unroll
        for (int r=0; r<4; ++r){
          int off = xsw(rf*16 + quad*4 + r, n);
          float rl = b2f(Yb[off]);
          float bez = c1*rl + c2*(Ya[rf][nt][r] + bb);
          Xa[off] = f2b(tanh_f(bez) * pv[rf][r]);
        }
      }
    }
    __syncthreads();   // Xa complete before next GEMM1; fences Yb readers vs next S2
  }
  // S5: resa = rlf(Xa) @ Wesa^T + besa -> v to Yb, E=exp(v) to Xa
  GEMM_TILE64(Xa, Wesa);
  __syncthreads();   // all GEMM reads of Xa(rlf) done before E overwrites it
  #pragma unroll
  for (int nt=0; nt<2; ++nt){
    int n = nbase + nt*16 + col;
    float be = besa[n];
    #pragma unroll
    for (int rf=0; rf<4; ++rf){
      #pragma unroll
      for (int r=0; r<4; ++r){
        int off = xsw(rf*16 + quad*4 + r, n);
        float v = Ya[rf][nt][r] + be;
        Yb[off] = f2b(v);            // resa value
        Xa[off] = f2b(__expf(v));    // E = exp(resa), once
      }
    }
  }
  __syncthreads();
  // G[row] = exp(gscore) (reads Yb) + SB column sums of E (reads Xa)
  {
    int m = tid >> 3, sub = tid & 7;   // 8 threads per row, 32 cols each
    if (m < 56){
      float s = 0.f;
      for (int e = sub*32; e < sub*32 + 32; ++e)
        s += b2f(Yb[xsw(m, e)]) * wmean[e];
      s += __shfl_xor(s, 1, 64);
      s += __shfl_xor(s, 2, 64);
      s += __shfl_xor(s, 4, 64);
      if (sub == 0)
        gsbp[m] = __expf(s + (bmu[0] + bmu[1] + bmu[2])*(1.f/3.f));
    }
  }
  {
    int jc = tid >> 8, o = tid & 255;  // all 512 threads
    float se = 0.f;
    for (int i=0;i<28;++i) se += b2f(Xa[xsw(i*2+jc, o)]);
    hrSBp[jc*256 + o] = 0.5f / se;
  }
  __syncthreads();
  if (tid < 2){
    int jc = tid;
    float se = 0.f;
    for (int i=0;i<28;++i) se += gsbp[i*2+jc];
    hrSGp[jc] = 0.5f / se;
  }
  __syncthreads();
  // masked output: atomicAdd straight into d_out (zeroed by k_prep)
  for (int it = tid; it < 7168; it += 512){
    int i = it >> 8, o = it & 255;
    if (i < cb){
      float s = 0.f;
      #pragma unroll
      for (int jc=0; jc<2; ++jc){
        int row = i*2 + jc;
        int off = xsw(row, o);
        float v = b2f(Yb[off]);
        float E = b2f(Xa[off]);
        float a = E*hrSBp[jc*256+o] + gsbp[row]*hrSGp[jc];
        s += a * v;
      }
      atomicAdd(&out[((size_t)b*28 + i)*256 + o], s);
    }
  }
}

extern "C" void kernel_launch(void* const* d_in, const int* in_sizes, int n_in,
                              void* d_out, int out_size, void* d_ws, size_t ws_size,
                              hipStream_t stream){
  const float* centers = (const float*)d_in[0];
  const float* emb     = (const float*)d_in[1];
  const int*   counts  = (const int*)d_in[2];
  const float* Wr      = (const float*)d_in[3];
  const float* br      = (const float*)d_in[4];
  const float* Wih     = (const float*)d_in[5];
  const float* Whh     = (const float*)d_in[6];
  const float* bih     = (const float*)d_in[7];
  const float* bhh     = (const float*)d_in[8];
  const float* Wgr     = (const float*)d_in[9];
  const float* bgr     = (const float*)d_in[10];
  const float* Wbc     = (const float*)d_in[11];
  const float* bbc     = (const float*)d_in[12];
  const float* alpha   = (const float*)d_in[13];
  const float* Wesa    = (const float*)d_in[14];
  const float* besa    = (const float*)d_in[15];
  const float* Wmu     = (const float*)d_in[16];
  const float* bmu     = (const float*)d_in[17];
  // d_in[18], d_in[19] (Wlv, blv) are dead at eval time.

  // ws layout (49,415,168 bytes total):
  unsigned short* olf   = (unsigned short*)d_ws;                      // 3*7168*256 bf16 = 11,010,048 B
  unsigned short* At    = (unsigned short*)((char*)d_ws + 11010048);  // 3*7168*512 bf16 = 22,020,096 B
  unsigned short* zx    = (unsigned short*)((char*)d_ws + 33030144);  // 7168*1024 bf16 = 14,680,064 B
  unsigned short* wcv   = (unsigned short*)((char*)d_ws + 47710208);  // 851,968 bf16 = 1,703,936 B
  float*          wmean = (float*)((char*)d_ws + 49414144);           // 256 f32
  unsigned short* cWih  = wcv;            // 262144 (N=1024)
  unsigned short* cWhh  = wcv + 262144;   // 262144 (N=1024)
  unsigned short* cWgri = wcv + 524288;   // 65536  (N=256)
  unsigned short* cWgrj = wcv + 589824;   // 65536  (N=256)
  unsigned short* cWgrr = wcv + 655360;   // 65536  (N=256)
  unsigned short* cWbc  = wcv + 720896;   // 65536  (N=256)
  unsigned short* cWesa = wcv + 786432;   // 65536  (N=256)
  float* outp = (float*)d_out;

  unsigned short* olf1 = olf + (size_t)7168*256;
  unsigned short* olf2 = olf + (size_t)2*7168*256;
  unsigned short* At1  = At  + (size_t)7168*512;
  unsigned short* At2  = At  + (size_t)2*7168*512;

  hipLaunchKernelGGL(k_repack7, dim3(3329), dim3(256), 0, stream,
                     Wih, Whh, Wgr, Wbc, Wesa, Wmu, wcv, wmean);
  hipLaunchKernelGGL(k_prep, dim3(7168), dim3(256), 0, stream, emb, counts, olf, outp);
  // LSTM pass 1 (olf0 -> olf1) fused with A-terms layer 0 (olf0 -> At0)
  hipLaunchKernelGGL(k_xgemm, dim3(224), dim3(256), 0, stream, olf, cWih, zx);
  hipLaunchKernelGGL(k_recat, dim3(44), dim3(1024), 0, stream,
                     zx, cWhh, bih, bhh, counts, olf1, olf, cWgri, cWgrj, At);
  // LSTM pass 2 (olf1 -> olf2) fused with A-terms layer 1 (olf1 -> At1)
  hipLaunchKernelGGL(k_xgemm, dim3(224), dim3(256), 0, stream, olf1, cWih, zx);
  hipLaunchKernelGGL(k_recat, dim3(44), dim3(1024), 0, stream,
                     zx, cWhh, bih, bhh, counts, olf2, olf1, cWgri, cWgrj, At1);
  // A-terms layer 2 (olf2 -> At2)
  hipLaunchKernelGGL(k_aterm, dim3(112), dim3(256), 0, stream, olf2, cWgri, cWgrj, At2);
  hipLaunchKernelGGL(k_mega,  dim3(3584), dim3(512), 0, stream,
                     centers, counts, Wr, br, cWgrr, bgr, cWbc, bbc, alpha,
                     cWesa, besa, wmean, bmu, At, outp);
}